// Round 19
// baseline (729.041 us; speedup 1.0000x reference)
//
#include <hip/hip_runtime.h>
#include <math.h>

// GraphNet: 2x EdgeConv (E=800k, F=H=64) + BN folded/commuted + pooling.
// R19 (final tuning): (a) pass2p inner loop 2->4 edges/iter (16 indep fdot2
// chains, 4 q-loads in flight) to hide node-boundary latency (VALU 70%->~85%);
// (b) xb dropped — ngemm256 reads f32 x directly (identical f2bf1 numerics).
// Everything else R18-verbatim (713us proven).

typedef unsigned short u16;
typedef unsigned int   u32;
typedef __bf16 bf16x8 __attribute__((ext_vector_type(8)));
typedef float  f32x4  __attribute__((ext_vector_type(4)));
typedef unsigned short us4 __attribute__((ext_vector_type(4)));
typedef _Float16 f16;
typedef f16 f16x2 __attribute__((ext_vector_type(2)));

#define EPSBN 1e-5f
#define PB_TOT 9344
// pblk: 0:stS1a[128] 128:stQ1a[128] 256:stS1b 320:stQ1b 384:stS2 448:stQ2
// 512:s1a[128] 640:t1a[128] 768:b1bF[64]
// 1088:gmax[4096] 5184:gsum[4096] 9280:cnt[64]

#if __has_builtin(__builtin_amdgcn_fdot2)
#define HAS_FDOT2 1
#else
#define HAS_FDOT2 0
#endif
#if __has_builtin(__builtin_amdgcn_readlane)
#define RLANE(v, l) ((u32)__builtin_amdgcn_readlane((int)(v), (l)))
#else
#define RLANE(v, l) ((u32)__shfl((int)(v), (l), 64))
#endif

__device__ __forceinline__ u32 f2bf1(float f){
    u32 u = __float_as_uint(f);
    return (u + 0x7FFFu + ((u >> 16) & 1u)) >> 16;
}
__device__ __forceinline__ float bf2f(u16 b){
    return __uint_as_float(((u32)b) << 16);
}
__device__ __forceinline__ void atomicMaxF(float* a, float v){
    if (v >= 0.f) atomicMax((int*)a, __float_as_int(v));
    else          atomicMin((u32*)a, __float_as_uint(v));
}
__device__ __forceinline__ int swz64(int row, int k){
    return row*64 + (k ^ ((row & 7) << 3));
}
__device__ __forceinline__ f32x4 mfma16(bf16x8 a, bf16x8 b, f32x4 c){
    return __builtin_amdgcn_mfma_f32_16x16x32_bf16(a, b, c, 0, 0, 0);
}
__device__ __forceinline__ float fdot2f(u32 h, f16x2 w, float acc){
#if HAS_FDOT2
    return __builtin_amdgcn_fdot2(__builtin_bit_cast(f16x2, h), w, acc, false);
#else
    f16x2 hh = __builtin_bit_cast(f16x2, h);
    acc = fmaf((float)hh[0], (float)w[0], acc);
    return fmaf((float)hh[1], (float)w[1], acc);
#endif
}

__global__ void k_init(float* __restrict__ agg, float* __restrict__ pblk,
                       int* __restrict__ deg, int NF, int N){
    int i = blockIdx.x*256 + threadIdx.x;
    if (i < NF) agg[i] = -INFINITY;
    if (i < N) deg[i] = 0;
    if (i < PB_TOT){
        pblk[i] = (i >= 1088 && i < 5184) ? -INFINITY : 0.f;
    }
}

__global__ void k_hist(const int* __restrict__ edst, int* __restrict__ deg, int E){
    int e = blockIdx.x*256 + threadIdx.x;
    if (e < E) atomicAdd(&deg[edst[e]], 1);
}

// 3-kernel parallel exclusive scan of deg -> cursor.
__global__ __launch_bounds__(1024) void k_scanA(const int* __restrict__ deg,
                                                int* __restrict__ cursor,
                                                int* __restrict__ bsum, int N){
    __shared__ int buf[1024];
    int tid = threadIdx.x;
    int i = blockIdx.x*1024 + tid;
    int v = (i < N) ? deg[i] : 0;
    buf[tid] = v;
    __syncthreads();
    #pragma unroll
    for (int s = 1; s < 1024; s <<= 1){
        int a = (tid >= s) ? buf[tid - s] : 0;
        __syncthreads();
        buf[tid] += a;
        __syncthreads();
    }
    if (i < N) cursor[i] = buf[tid] - v;
    if (tid == 1023) bsum[blockIdx.x] = buf[1023];
}
__global__ void k_scanB(const int* __restrict__ bsum, int* __restrict__ boff, int nblk){
    if (threadIdx.x == 0){
        int run = 0;
        for (int i = 0; i < nblk; ++i){ boff[i] = run; run += bsum[i]; }
    }
}
__global__ __launch_bounds__(1024) void k_scanC(int* __restrict__ cursor,
                                                const int* __restrict__ boff, int N){
    int i = blockIdx.x*1024 + threadIdx.x;
    if (i < N) cursor[i] += boff[blockIdx.x];
}

__global__ void k_scatter(const int* __restrict__ esrc, const int* __restrict__ edst,
                          int* __restrict__ cursor, int* __restrict__ eps, int E){
    int e = blockIdx.x*256 + threadIdx.x;
    if (e < E){
        int d = edst[e];
        int pos = atomicAdd(&cursor[d], 1);
        eps[pos] = esrc[e];
    }
}

// Node GEMM -> PQ table. IFMT=0: u16-bf16 input; IFMT=1: f32 input.
// FMT=0: bf16 out; FMT=1: f16 out.
template<int COUT, int FMT, int IFMT>
__global__ __launch_bounds__(256) void k_ngemm(
    const void* __restrict__ xin_, const float* __restrict__ Wsrc,
    const float* __restrict__ bias, u16* __restrict__ PQ, int N)
{
    const int WC = COUT/2;
    __shared__ u16 Wt[COUT*64];
    __shared__ u16 At[64*64];
    int tid = threadIdx.x;
    for (int i = tid; i < COUT*64; i += 256){
        int c = i >> 6, k = i & 63;
        float w = (c < WC) ? (Wsrc[k*WC + c] - Wsrc[(64+k)*WC + c])
                           : Wsrc[(64+k)*WC + (c - WC)];
        Wt[swz64(c, k)] = (u16)f2bf1(w);
    }
    int t = blockIdx.x;
    for (int i = tid; i < 512; i += 256){
        int row = i >> 3, ck = i & 7;
        int node = t*64 + row;
        uint4 v;
        if (node < N){
            if (IFMT){
                const float* xf = (const float*)xin_ + (size_t)node*64 + ck*8;
                float4 f0 = *(const float4*)xf;
                float4 f1 = *(const float4*)(xf + 4);
                v.x = f2bf1(f0.x) | (f2bf1(f0.y) << 16);
                v.y = f2bf1(f0.z) | (f2bf1(f0.w) << 16);
                v.z = f2bf1(f1.x) | (f2bf1(f1.y) << 16);
                v.w = f2bf1(f1.z) | (f2bf1(f1.w) << 16);
            } else {
                v = *(const uint4*)((const u16*)xin_ + (size_t)node*64 + ck*8);
            }
        } else { v.x = v.y = v.z = v.w = 0u; }
        *(uint4*)&At[swz64(row, ck*8)] = v;
    }
    __syncthreads();
    int lane = tid & 63, wave = tid >> 6;
    int lg = lane >> 4, lr = lane & 15;
    int row = wave*16 + lr;
    bf16x8 bfr[2];
    #pragma unroll
    for (int kt = 0; kt < 2; kt++)
        bfr[kt] = *(const bf16x8*)&At[swz64(row, kt*32 + lg*8)];
    int node = t*64 + wave*16 + lr;
    #pragma unroll
    for (int mt = 0; mt < COUT/16; mt++){
        f32x4 acc = {0.f,0.f,0.f,0.f};
        #pragma unroll
        for (int kt = 0; kt < 2; kt++){
            bf16x8 af = *(const bf16x8*)&Wt[swz64(mt*16 + lr, kt*32 + lg*8)];
            acc = mfma16(af, bfr[kt], acc);
        }
        int ch = mt*16 + lg*4;
        float r[4] = {acc[0], acc[1], acc[2], acc[3]};
        if (ch < WC){
            float4 bb = *(const float4*)(bias + ch);
            r[0] += bb.x; r[1] += bb.y; r[2] += bb.z; r[3] += bb.w;
        }
        if (node < N){
            us4 w4;
            #pragma unroll
            for (int j = 0; j < 4; j++){
                if (FMT){
                    f16 hf = (f16)r[j];
                    w4[j] = __builtin_bit_cast(u16, hf);
                } else {
                    w4[j] = (u16)f2bf1(r[j]);
                }
            }
            *(us4*)(PQ + (size_t)node*COUT + ch) = w4;
        }
    }
}

// pass1p: pull BN1a stats from f16 PQ1; 4 edges/iter.
__global__ __launch_bounds__(256) void k_pass1p(
    const u16* __restrict__ PQ1, const int* __restrict__ eps,
    const int* __restrict__ cursor, const int* __restrict__ deg,
    float* __restrict__ pblk, int N)
{
    int tid = threadIdx.x;
    int lane = tid & 63, wave = tid >> 6;
    float s0 = 0.f, s1 = 0.f, q0 = 0.f, q1 = 0.f;

    for (int n = blockIdx.x*4 + wave; n < N; n += gridDim.x*4){
        int d  = deg[n];
        int r0 = cursor[n] - d;
        f16x2 pv = *(const f16x2*)(PQ1 + (size_t)n*256 + 2*lane);
        int i = 0;
        for (; i + 3 < d; i += 4){
            int sA = eps[r0+i], sB = eps[r0+i+1], sC = eps[r0+i+2], sD = eps[r0+i+3];
            f16x2 qA = *(const f16x2*)(PQ1 + (size_t)sA*256 + 128 + 2*lane);
            f16x2 qB = *(const f16x2*)(PQ1 + (size_t)sB*256 + 128 + 2*lane);
            f16x2 qC = *(const f16x2*)(PQ1 + (size_t)sC*256 + 128 + 2*lane);
            f16x2 qD = *(const f16x2*)(PQ1 + (size_t)sD*256 + 128 + 2*lane);
            f16x2 hA = pv + qA, hB = pv + qB, hC = pv + qC, hD = pv + qD;
            float a0 = fmaxf((float)hA[0], 0.f), a1 = fmaxf((float)hA[1], 0.f);
            float b0 = fmaxf((float)hB[0], 0.f), b1 = fmaxf((float)hB[1], 0.f);
            float c0 = fmaxf((float)hC[0], 0.f), c1 = fmaxf((float)hC[1], 0.f);
            float e0 = fmaxf((float)hD[0], 0.f), e1 = fmaxf((float)hD[1], 0.f);
            s0 += (a0 + b0) + (c0 + e0); s1 += (a1 + b1) + (c1 + e1);
            q0 = fmaf(a0, a0, q0); q0 = fmaf(b0, b0, q0);
            q0 = fmaf(c0, c0, q0); q0 = fmaf(e0, e0, q0);
            q1 = fmaf(a1, a1, q1); q1 = fmaf(b1, b1, q1);
            q1 = fmaf(c1, c1, q1); q1 = fmaf(e1, e1, q1);
        }
        for (; i < d; ++i){
            int sA = eps[r0 + i];
            f16x2 qA = *(const f16x2*)(PQ1 + (size_t)sA*256 + 128 + 2*lane);
            f16x2 hA = pv + qA;
            float a0 = fmaxf((float)hA[0], 0.f), a1 = fmaxf((float)hA[1], 0.f);
            s0 += a0; s1 += a1;
            q0 = fmaf(a0, a0, q0);
            q1 = fmaf(a1, a1, q1);
        }
    }
    __shared__ float bS0[256], bS1[256], bQ0[256], bQ1[256];
    bS0[tid] = s0; bS1[tid] = s1; bQ0[tid] = q0; bQ1[tid] = q1;
    __syncthreads();
    if (wave == 0){
        float a0 = bS0[lane] + bS0[64+lane] + bS0[128+lane] + bS0[192+lane];
        float a1 = bS1[lane] + bS1[64+lane] + bS1[128+lane] + bS1[192+lane];
        float c0 = bQ0[lane] + bQ0[64+lane] + bQ0[128+lane] + bQ0[192+lane];
        float c1 = bQ1[lane] + bQ1[64+lane] + bQ1[128+lane] + bQ1[192+lane];
        atomicAdd(&pblk[2*lane],       a0);
        atomicAdd(&pblk[2*lane + 1],   a1);
        atomicAdd(&pblk[128 + 2*lane],     c0);
        atomicAdd(&pblk[128 + 2*lane + 1], c1);
    }
}

__global__ void k_fold1(const float* __restrict__ g1a, const float* __restrict__ bt1a,
                        const float* __restrict__ W1b, const float* __restrict__ b1b,
                        float* __restrict__ pblk, float fE)
{
    __shared__ float tS[128];
    int tid = threadIdx.x;
    if (tid < 128){
        float m = pblk[tid] * fE;
        float q = pblk[128 + tid] * fE;
        float v = fmaxf(q - m*m, 0.f);
        float s = g1a[tid] * rsqrtf(v + EPSBN);
        float t = bt1a[tid] - m*s;
        pblk[512 + tid] = s;
        pblk[640 + tid] = t;
        tS[tid] = t;
    }
    __syncthreads();
    if (tid < 64){
        float acc = b1b[tid];
        for (int k = 0; k < 128; k++) acc = fmaf(tS[k], W1b[k*64 + tid], acc);
        pblk[768 + tid] = acc;
    }
}

// pass2p: pull GEMM-b, 4 edges/iter x 4 accumulators each (16 indep chains);
// readlane + fdot2.
__global__ __launch_bounds__(256) void k_pass2p(
    const u16* __restrict__ PQ1, const int* __restrict__ eps,
    const int* __restrict__ cursor, const int* __restrict__ deg,
    const float* __restrict__ W1b,
    float* __restrict__ pblk, float* __restrict__ agg, int N)
{
    int tid = threadIdx.x;
    int lane = tid & 63, wave = tid >> 6;
    f16x2 wh[64];
    #pragma unroll
    for (int kk = 0; kk < 64; kk++){
        float w0 = pblk[512 + 2*kk]     * W1b[(2*kk)*64 + lane];
        float w1 = pblk[512 + 2*kk + 1] * W1b[(2*kk + 1)*64 + lane];
        f16x2 t; t[0] = (f16)w0; t[1] = (f16)w1;
        wh[kk] = t;
    }
    float bc = pblk[768 + lane];
    float runS = 0.f, runQ = 0.f;
    const f16 z0 = (f16)0;

    for (int n = blockIdx.x*4 + wave; n < N; n += gridDim.x*4){
        int d  = deg[n];
        int r0 = cursor[n] - d;
        f16x2 pv = *(const f16x2*)(PQ1 + (size_t)n*256 + 2*lane);
        float mh = -INFINITY;
        int i = 0;
        for (; i + 3 < d; i += 4){
            int sA = eps[r0+i], sB = eps[r0+i+1], sC = eps[r0+i+2], sD = eps[r0+i+3];
            f16x2 qA = *(const f16x2*)(PQ1 + (size_t)sA*256 + 128 + 2*lane);
            f16x2 qB = *(const f16x2*)(PQ1 + (size_t)sB*256 + 128 + 2*lane);
            f16x2 qC = *(const f16x2*)(PQ1 + (size_t)sC*256 + 128 + 2*lane);
            f16x2 qD = *(const f16x2*)(PQ1 + (size_t)sD*256 + 128 + 2*lane);
            f16x2 hA = pv + qA, hB = pv + qB, hC = pv + qC, hD = pv + qD;
            hA[0] = hA[0] > z0 ? hA[0] : z0;  hA[1] = hA[1] > z0 ? hA[1] : z0;
            hB[0] = hB[0] > z0 ? hB[0] : z0;  hB[1] = hB[1] > z0 ? hB[1] : z0;
            hC[0] = hC[0] > z0 ? hC[0] : z0;  hC[1] = hC[1] > z0 ? hC[1] : z0;
            hD[0] = hD[0] > z0 ? hD[0] : z0;  hD[1] = hD[1] > z0 ? hD[1] : z0;
            u32 hpA = __builtin_bit_cast(u32, hA);
            u32 hpB = __builtin_bit_cast(u32, hB);
            u32 hpC = __builtin_bit_cast(u32, hC);
            u32 hpD = __builtin_bit_cast(u32, hD);
            float aA[4] = {0.f,0.f,0.f,0.f};
            float aB[4] = {0.f,0.f,0.f,0.f};
            float aC[4] = {0.f,0.f,0.f,0.f};
            float aD[4] = {0.f,0.f,0.f,0.f};
            #pragma unroll
            for (int kk = 0; kk < 64; kk++){
                u32 xA = RLANE(hpA, kk);
                u32 xB = RLANE(hpB, kk);
                u32 xC = RLANE(hpC, kk);
                u32 xD = RLANE(hpD, kk);
                aA[kk & 3] = fdot2f(xA, wh[kk], aA[kk & 3]);
                aB[kk & 3] = fdot2f(xB, wh[kk], aB[kk & 3]);
                aC[kk & 3] = fdot2f(xC, wh[kk], aC[kk & 3]);
                aD[kk & 3] = fdot2f(xD, wh[kk], aD[kk & 3]);
            }
            float hbA = fmaxf((aA[0]+aA[1]) + (aA[2]+aA[3]) + bc, 0.f);
            float hbB = fmaxf((aB[0]+aB[1]) + (aB[2]+aB[3]) + bc, 0.f);
            float hbC = fmaxf((aC[0]+aC[1]) + (aC[2]+aC[3]) + bc, 0.f);
            float hbD = fmaxf((aD[0]+aD[1]) + (aD[2]+aD[3]) + bc, 0.f);
            runS += (hbA + hbB) + (hbC + hbD);
            runQ = fmaf(hbA, hbA, runQ); runQ = fmaf(hbB, hbB, runQ);
            runQ = fmaf(hbC, hbC, runQ); runQ = fmaf(hbD, hbD, runQ);
            mh = fmaxf(mh, fmaxf(fmaxf(hbA, hbB), fmaxf(hbC, hbD)));
        }
        for (; i < d; ++i){
            int sA = eps[r0 + i];
            f16x2 qA = *(const f16x2*)(PQ1 + (size_t)sA*256 + 128 + 2*lane);
            f16x2 hA = pv + qA;
            hA[0] = hA[0] > z0 ? hA[0] : z0;  hA[1] = hA[1] > z0 ? hA[1] : z0;
            u32 hpA = __builtin_bit_cast(u32, hA);
            float aA[4] = {0.f,0.f,0.f,0.f};
            #pragma unroll
            for (int kk = 0; kk < 64; kk++){
                u32 xA = RLANE(hpA, kk);
                aA[kk & 3] = fdot2f(xA, wh[kk], aA[kk & 3]);
            }
            float hbA = fmaxf((aA[0]+aA[1]) + (aA[2]+aA[3]) + bc, 0.f);
            runS += hbA;
            runQ = fmaf(hbA, hbA, runQ);
            mh = fmaxf(mh, hbA);
        }
        if (d > 0) agg[(size_t)n*64 + lane] = mh;
    }
    __shared__ float bS[256], bQ[256];
    bS[tid] = runS; bQ[tid] = runQ;
    __syncthreads();
    if (wave == 0){
        float s = bS[lane] + bS[64+lane] + bS[128+lane] + bS[192+lane];
        float q = bQ[lane] + bQ[64+lane] + bQ[128+lane] + bQ[192+lane];
        atomicAdd(&pblk[256 + lane], s);
        atomicAdd(&pblk[320 + lane], q);
    }
}

// x1 = relu(bn1b(agg) or 0) -> x1b; BN1b affine inline. Resets agg.
__global__ void k_x1(float* __restrict__ agg, const float* __restrict__ pblk,
                     const float* __restrict__ g1b, const float* __restrict__ bt1b,
                     float fE, u16* __restrict__ x1b, int NF)
{
    int i = blockIdx.x*256 + threadIdx.x;
    if (i >= NF) return;
    int c = i & 63;
    float m = pblk[256 + c] * fE;
    float q = pblk[320 + c] * fE;
    float vv = fmaxf(q - m*m, 0.f);
    float s = g1b[c] * rsqrtf(vv + EPSBN);
    float t = bt1b[c] - m*s;
    float a = agg[i];
    float v = (a > -INFINITY) ? fmaf(a, s, t) : 0.f;
    v = fmaxf(v, 0.f);
    x1b[i] = (u16)f2bf1(v);
    agg[i] = -INFINITY;
}

// pass3p: pull conv2 (stats2 + segmax Q2), 4 edges/iter.
__global__ __launch_bounds__(256) void k_pass3p(
    const u16* __restrict__ PQ2, const int* __restrict__ eps,
    const int* __restrict__ cursor, const int* __restrict__ deg,
    float* __restrict__ pblk, float* __restrict__ agg, int N)
{
    int tid = threadIdx.x;
    int lane = tid & 63, wave = tid >> 6;
    float runS = 0.f, runQ = 0.f;

    for (int n = blockIdx.x*4 + wave; n < N; n += gridDim.x*4){
        int d  = deg[n];
        int r0 = cursor[n] - d;
        float p = bf2f(PQ2[(size_t)n*128 + lane]);
        float mq = -INFINITY;
        int i = 0;
        for (; i + 3 < d; i += 4){
            int sA = eps[r0+i], sB = eps[r0+i+1], sC = eps[r0+i+2], sD = eps[r0+i+3];
            float qA = bf2f(PQ2[(size_t)sA*128 + 64 + lane]);
            float qB = bf2f(PQ2[(size_t)sB*128 + 64 + lane]);
            float qC = bf2f(PQ2[(size_t)sC*128 + 64 + lane]);
            float qD = bf2f(PQ2[(size_t)sD*128 + 64 + lane]);
            mq = fmaxf(mq, fmaxf(fmaxf(qA, qB), fmaxf(qC, qD)));
            float hA = fmaxf(p + qA, 0.f), hB = fmaxf(p + qB, 0.f);
            float hC = fmaxf(p + qC, 0.f), hD = fmaxf(p + qD, 0.f);
            runS += (hA + hB) + (hC + hD);
            runQ = fmaf(hA, hA, runQ); runQ = fmaf(hB, hB, runQ);
            runQ = fmaf(hC, hC, runQ); runQ = fmaf(hD, hD, runQ);
        }
        for (; i < d; ++i){
            int sA = eps[r0 + i];
            float qA = bf2f(PQ2[(size_t)sA*128 + 64 + lane]);
            mq = fmaxf(mq, qA);
            float hA = fmaxf(p + qA, 0.f);
            runS += hA;
            runQ = fmaf(hA, hA, runQ);
        }
        if (d > 0) agg[(size_t)n*64 + lane] = mq;
    }
    __shared__ float bS[256], bQ[256];
    bS[tid] = runS; bQ[tid] = runQ;
    __syncthreads();
    if (wave == 0){
        float s = bS[lane] + bS[64 + lane] + bS[128 + lane] + bS[192 + lane];
        float q = bQ[lane] + bQ[64 + lane] + bQ[128 + lane] + bQ[192 + lane];
        atomicAdd(&pblk[384 + lane], s);
        atomicAdd(&pblk[448 + lane], q);
    }
}

// k_fuse: BN2 affine inline; x2 reconstructed from maxQ2+P2; graph pooling.
#define FUSE_NODES 32
__global__ __launch_bounds__(256) void k_fuse(const float* __restrict__ agg,
                                              const u16* __restrict__ x1b,
                                              const u16* __restrict__ PQ2,
                                              const int* __restrict__ batch,
                                              const float* __restrict__ g2,
                                              const float* __restrict__ bt2,
                                              float fE,
                                              float* __restrict__ pblk, int N)
{
    int c = threadIdx.x & 63, r = threadIdx.x >> 6;
    int n0 = blockIdx.x*FUSE_NODES + r*(FUSE_NODES/4);
    if (n0 >= N) return;
    int n1 = n0 + FUSE_NODES/4; if (n1 > N) n1 = N;
    float m2 = pblk[384 + c] * fE;
    float q2 = pblk[448 + c] * fE;
    float vv = fmaxf(q2 - m2*m2, 0.f);
    float s2c = g2[c] * rsqrtf(vv + EPSBN);
    float t2c = bt2[c] - m2*s2c;
    float gm = -INFINITY, gs = 0.f;
    int cur = batch[n0], cnt0 = 0;
    for (int n = n0; n < n1; ++n){
        int g = batch[n];
        if (g != cur){
            atomicMaxF(&pblk[1088 + cur*64 + c], gm);
            atomicAdd(&pblk[5184 + cur*64 + c], gs);
            if (c == 0) atomicAdd(&pblk[9280 + cur], (float)cnt0);
            gm = -INFINITY; gs = 0.f; cnt0 = 0; cur = g;
        }
        float a = agg[(size_t)n*64 + c];
        float v;
        if (a > -INFINITY){
            float p = bf2f(PQ2[(size_t)n*128 + c]);
            float pre = fmaxf(p + a, 0.f);
            v = fmaxf(fmaf(pre, s2c, t2c), 0.f);
        } else v = 0.f;
        float f = bf2f(x1b[(size_t)n*64 + c]) + v;
        gm = fmaxf(gm, f); gs += f; cnt0++;
    }
    atomicMaxF(&pblk[1088 + cur*64 + c], gm);
    atomicAdd(&pblk[5184 + cur*64 + c], gs);
    if (c == 0) atomicAdd(&pblk[9280 + cur], (float)cnt0);
}

__global__ void k_out(const float* __restrict__ pblk, float* __restrict__ out)
{
    int i = blockIdx.x*256 + threadIdx.x;
    if (i >= 64*128) return;
    int g = i >> 7, c = i & 127;
    float r;
    if (c < 64){
        float m = pblk[1088 + g*64 + c];
        r = (m > -INFINITY) ? m : 0.f;
    } else {
        float s = pblk[5184 + g*64 + (c - 64)];
        float n = pblk[9280 + g];
        r = s / fmaxf(n, 1.f);
    }
    out[i] = r;
}

extern "C" void kernel_launch(void* const* d_in, const int* in_sizes, int n_in,
                              void* d_out, int out_size, void* d_ws, size_t ws_size,
                              hipStream_t stream)
{
    const float* x    = (const float*)d_in[0];
    const int*   ei   = (const int*)  d_in[1];
    const int*   batch= (const int*)  d_in[2];
    const float* W1a  = (const float*)d_in[3];
    const float* b1a  = (const float*)d_in[4];
    const float* g1a  = (const float*)d_in[5];
    const float* bt1a = (const float*)d_in[6];
    const float* W1b  = (const float*)d_in[7];
    const float* b1b  = (const float*)d_in[8];
    const float* g1b  = (const float*)d_in[9];
    const float* bt1b = (const float*)d_in[10];
    const float* W2   = (const float*)d_in[11];
    const float* b2   = (const float*)d_in[12];
    const float* g2   = (const float*)d_in[13];
    const float* bt2  = (const float*)d_in[14];

    int N  = in_sizes[0] / 64;
    int E  = in_sizes[1] / 2;
    int NF = N * 64;

    char* ws = (char*)d_ws;
    size_t off = 0;
    auto alloc = [&](size_t bytes){ size_t o = off; off += (bytes + 255) & ~(size_t)255; return o; };
    u16*   x1b   = (u16*)  (ws + alloc((size_t)NF*2));
    float* agg   = (float*)(ws + alloc((size_t)NF*4));
    float* pblk  = (float*)(ws + alloc((size_t)PB_TOT*4));
    int*   deg   = (int*)  (ws + alloc((size_t)N*4));
    int*   cursor= (int*)  (ws + alloc((size_t)N*4));
    int*   eps   = (int*)  (ws + alloc((size_t)E*4));
    u16*   PQ1   = (u16*)  (ws + alloc((size_t)N*256*2));
    u16*   PQ2   = (u16*)  (ws + alloc((size_t)N*128*2));
    int*   bsum  = (int*)  (ws + alloc((size_t)1024*4));
    int*   boff  = (int*)  (ws + alloc((size_t)1024*4));
    (void)ws_size;   // ~62MB << proven 237.7MB budget

    const int* esrc = ei;
    const int* edst = ei + E;
    int gElem  = (NF + 255) / 256;
    int gEdge  = (E + 255) / 256;
    int gNode  = (N + 63) / 64;
    int gScan  = (N + 1023) / 1024;
    int gPull  = ((N + 3) / 4) < 2048 ? ((N + 3) / 4) : 2048;
    float fE   = 1.f / (float)E;

    k_init          <<<gElem, 256, 0, stream>>>(agg, pblk, deg, NF, N);
    k_hist          <<<gEdge, 256, 0, stream>>>(edst, deg, E);
    k_scanA         <<<gScan, 1024, 0, stream>>>(deg, cursor, bsum, N);
    k_scanB         <<<1, 64, 0, stream>>>(bsum, boff, gScan);
    k_scanC         <<<gScan, 1024, 0, stream>>>(cursor, boff, N);
    k_scatter       <<<gEdge, 256, 0, stream>>>(esrc, edst, cursor, eps, E);
    k_ngemm<256,1,1><<<gNode, 256, 0, stream>>>(x, W1a, b1a, PQ1, N);
    k_pass1p        <<<gPull, 256, 0, stream>>>(PQ1, eps, cursor, deg, pblk, N);
    k_fold1         <<<1, 128, 0, stream>>>(g1a, bt1a, W1b, b1b, pblk, fE);
    k_pass2p        <<<gPull, 256, 0, stream>>>(PQ1, eps, cursor, deg, W1b, pblk, agg, N);
    k_x1            <<<gElem, 256, 0, stream>>>(agg, pblk, g1b, bt1b, fE, x1b, NF);
    k_ngemm<128,0,0><<<gNode, 256, 0, stream>>>(x1b, W2, b2, PQ2, N);
    k_pass3p        <<<gPull, 256, 0, stream>>>(PQ2, eps, cursor, deg, pblk, agg, N);
    k_fuse          <<<(N + FUSE_NODES - 1)/FUSE_NODES, 256, 0, stream>>>(agg, x1b, PQ2, batch, g2, bt2, fE, pblk, N);
    k_out           <<<32, 256, 0, stream>>>(pblk, (float*)d_out);
}

// Round 20
// 714.868 us; speedup vs baseline: 1.0198x; 1.0198x over previous
//
#include <hip/hip_runtime.h>
#include <math.h>

// GraphNet: 2x EdgeConv (E=800k, F=H=64) + BN folded/commuted + pooling.
// FINAL (R18 config, 713us proven, 5.4x over baseline):
//  - EdgeConv linearized: per-node tables P=x@(Wtop-Wbot)+b, Q=x@Wbot (MFMA
//    node GEMMs); h_edge = relu(P[dst]+Q[src]) — no per-edge GEMM-a.
//  - All edge passes PULL-based over dst-sorted CSR (counting sort): the
//    push-tile shape cost ~890us regardless of content; pull broke it.
//  - pass2p: lane=channel in-register GEMM-b via v_readlane (scalar-pipe
//    broadcast; ds_bpermute was the bottleneck) + v_dot2_f32_f16,
//    2 edges x 4 accumulators = 8 indep chains. 281us @ 70% VALUBusy
//    (~issue floor). MFMA variant refuted (R17: deg-16 starves matrix pipe).
//  - conv2: segmax relu(P2[d]+Q2[s]) = relu(P2[d]+segmax Q2[s]) — pass3p
//    scatters only max Q2; k_fuse reconstructs x2 and pools per graph run.
//  - BN affines inlined from raw sum/sumsq stats (fold absorbed).

typedef unsigned short u16;
typedef unsigned int   u32;
typedef __bf16 bf16x8 __attribute__((ext_vector_type(8)));
typedef float  f32x4  __attribute__((ext_vector_type(4)));
typedef unsigned short us4 __attribute__((ext_vector_type(4)));
typedef _Float16 f16;
typedef f16 f16x2 __attribute__((ext_vector_type(2)));

#define EPSBN 1e-5f
#define PB_TOT 9344
// pblk: 0:stS1a[128] 128:stQ1a[128] 256:stS1b 320:stQ1b 384:stS2 448:stQ2
// 512:s1a[128] 640:t1a[128] 768:b1bF[64]
// 1088:gmax[4096] 5184:gsum[4096] 9280:cnt[64]

#if __has_builtin(__builtin_amdgcn_fdot2)
#define HAS_FDOT2 1
#else
#define HAS_FDOT2 0
#endif
#if __has_builtin(__builtin_amdgcn_readlane)
#define RLANE(v, l) ((u32)__builtin_amdgcn_readlane((int)(v), (l)))
#else
#define RLANE(v, l) ((u32)__shfl((int)(v), (l), 64))
#endif

__device__ __forceinline__ u32 f2bf1(float f){
    u32 u = __float_as_uint(f);
    return (u + 0x7FFFu + ((u >> 16) & 1u)) >> 16;
}
__device__ __forceinline__ float bf2f(u16 b){
    return __uint_as_float(((u32)b) << 16);
}
__device__ __forceinline__ void atomicMaxF(float* a, float v){
    if (v >= 0.f) atomicMax((int*)a, __float_as_int(v));
    else          atomicMin((u32*)a, __float_as_uint(v));
}
__device__ __forceinline__ int swz64(int row, int k){
    return row*64 + (k ^ ((row & 7) << 3));
}
__device__ __forceinline__ f32x4 mfma16(bf16x8 a, bf16x8 b, f32x4 c){
    return __builtin_amdgcn_mfma_f32_16x16x32_bf16(a, b, c, 0, 0, 0);
}
__device__ __forceinline__ float fdot2f(u32 h, f16x2 w, float acc){
#if HAS_FDOT2
    return __builtin_amdgcn_fdot2(__builtin_bit_cast(f16x2, h), w, acc, false);
#else
    f16x2 hh = __builtin_bit_cast(f16x2, h);
    acc = fmaf((float)hh[0], (float)w[0], acc);
    return fmaf((float)hh[1], (float)w[1], acc);
#endif
}

__global__ void k_init(const float* __restrict__ x, u16* __restrict__ xb,
                       float* __restrict__ agg,
                       float* __restrict__ pblk, int* __restrict__ deg,
                       int NF, int N){
    int i = blockIdx.x*256 + threadIdx.x;
    if (i < NF){
        xb[i] = (u16)f2bf1(x[i]);
        agg[i] = -INFINITY;
    }
    if (i < N) deg[i] = 0;
    if (i < PB_TOT){
        pblk[i] = (i >= 1088 && i < 5184) ? -INFINITY : 0.f;
    }
}

__global__ void k_hist(const int* __restrict__ edst, int* __restrict__ deg, int E){
    int e = blockIdx.x*256 + threadIdx.x;
    if (e < E) atomicAdd(&deg[edst[e]], 1);
}

// 3-kernel parallel exclusive scan of deg -> cursor.
__global__ __launch_bounds__(1024) void k_scanA(const int* __restrict__ deg,
                                                int* __restrict__ cursor,
                                                int* __restrict__ bsum, int N){
    __shared__ int buf[1024];
    int tid = threadIdx.x;
    int i = blockIdx.x*1024 + tid;
    int v = (i < N) ? deg[i] : 0;
    buf[tid] = v;
    __syncthreads();
    #pragma unroll
    for (int s = 1; s < 1024; s <<= 1){
        int a = (tid >= s) ? buf[tid - s] : 0;
        __syncthreads();
        buf[tid] += a;
        __syncthreads();
    }
    if (i < N) cursor[i] = buf[tid] - v;
    if (tid == 1023) bsum[blockIdx.x] = buf[1023];
}
__global__ void k_scanB(const int* __restrict__ bsum, int* __restrict__ boff, int nblk){
    if (threadIdx.x == 0){
        int run = 0;
        for (int i = 0; i < nblk; ++i){ boff[i] = run; run += bsum[i]; }
    }
}
__global__ __launch_bounds__(1024) void k_scanC(int* __restrict__ cursor,
                                                const int* __restrict__ boff, int N){
    int i = blockIdx.x*1024 + threadIdx.x;
    if (i < N) cursor[i] += boff[blockIdx.x];
}

__global__ void k_scatter(const int* __restrict__ esrc, const int* __restrict__ edst,
                          int* __restrict__ cursor, int* __restrict__ eps, int E){
    int e = blockIdx.x*256 + threadIdx.x;
    if (e < E){
        int d = edst[e];
        int pos = atomicAdd(&cursor[d], 1);
        eps[pos] = esrc[e];
    }
}

// Node GEMM -> PQ table. FMT=0: bf16 out; FMT=1: f16 out.
template<int COUT, int FMT>
__global__ __launch_bounds__(256) void k_ngemm(
    const u16* __restrict__ xin, const float* __restrict__ Wsrc,
    const float* __restrict__ bias, u16* __restrict__ PQ, int N)
{
    const int WC = COUT/2;
    __shared__ u16 Wt[COUT*64];
    __shared__ u16 At[64*64];
    int tid = threadIdx.x;
    for (int i = tid; i < COUT*64; i += 256){
        int c = i >> 6, k = i & 63;
        float w = (c < WC) ? (Wsrc[k*WC + c] - Wsrc[(64+k)*WC + c])
                           : Wsrc[(64+k)*WC + (c - WC)];
        Wt[swz64(c, k)] = (u16)f2bf1(w);
    }
    int t = blockIdx.x;
    for (int i = tid; i < 512; i += 256){
        int row = i >> 3, ck = i & 7;
        int node = t*64 + row;
        uint4 v;
        if (node < N) v = *(const uint4*)(xin + (size_t)node*64 + ck*8);
        else { v.x = v.y = v.z = v.w = 0u; }
        *(uint4*)&At[swz64(row, ck*8)] = v;
    }
    __syncthreads();
    int lane = tid & 63, wave = tid >> 6;
    int lg = lane >> 4, lr = lane & 15;
    int row = wave*16 + lr;
    bf16x8 bfr[2];
    #pragma unroll
    for (int kt = 0; kt < 2; kt++)
        bfr[kt] = *(const bf16x8*)&At[swz64(row, kt*32 + lg*8)];
    int node = t*64 + wave*16 + lr;
    #pragma unroll
    for (int mt = 0; mt < COUT/16; mt++){
        f32x4 acc = {0.f,0.f,0.f,0.f};
        #pragma unroll
        for (int kt = 0; kt < 2; kt++){
            bf16x8 af = *(const bf16x8*)&Wt[swz64(mt*16 + lr, kt*32 + lg*8)];
            acc = mfma16(af, bfr[kt], acc);
        }
        int ch = mt*16 + lg*4;
        float r[4] = {acc[0], acc[1], acc[2], acc[3]};
        if (ch < WC){
            float4 bb = *(const float4*)(bias + ch);
            r[0] += bb.x; r[1] += bb.y; r[2] += bb.z; r[3] += bb.w;
        }
        if (node < N){
            us4 w4;
            #pragma unroll
            for (int j = 0; j < 4; j++){
                if (FMT){
                    f16 hf = (f16)r[j];
                    w4[j] = __builtin_bit_cast(u16, hf);
                } else {
                    w4[j] = (u16)f2bf1(r[j]);
                }
            }
            *(us4*)(PQ + (size_t)node*COUT + ch) = w4;
        }
    }
}

// pass1p: pull BN1a stats from f16 PQ1; 4 edges/iter.
__global__ __launch_bounds__(256) void k_pass1p(
    const u16* __restrict__ PQ1, const int* __restrict__ eps,
    const int* __restrict__ cursor, const int* __restrict__ deg,
    float* __restrict__ pblk, int N)
{
    int tid = threadIdx.x;
    int lane = tid & 63, wave = tid >> 6;
    float s0 = 0.f, s1 = 0.f, q0 = 0.f, q1 = 0.f;

    for (int n = blockIdx.x*4 + wave; n < N; n += gridDim.x*4){
        int d  = deg[n];
        int r0 = cursor[n] - d;
        f16x2 pv = *(const f16x2*)(PQ1 + (size_t)n*256 + 2*lane);
        int i = 0;
        for (; i + 3 < d; i += 4){
            int sA = eps[r0+i], sB = eps[r0+i+1], sC = eps[r0+i+2], sD = eps[r0+i+3];
            f16x2 qA = *(const f16x2*)(PQ1 + (size_t)sA*256 + 128 + 2*lane);
            f16x2 qB = *(const f16x2*)(PQ1 + (size_t)sB*256 + 128 + 2*lane);
            f16x2 qC = *(const f16x2*)(PQ1 + (size_t)sC*256 + 128 + 2*lane);
            f16x2 qD = *(const f16x2*)(PQ1 + (size_t)sD*256 + 128 + 2*lane);
            f16x2 hA = pv + qA, hB = pv + qB, hC = pv + qC, hD = pv + qD;
            float a0 = fmaxf((float)hA[0], 0.f), a1 = fmaxf((float)hA[1], 0.f);
            float b0 = fmaxf((float)hB[0], 0.f), b1 = fmaxf((float)hB[1], 0.f);
            float c0 = fmaxf((float)hC[0], 0.f), c1 = fmaxf((float)hC[1], 0.f);
            float e0 = fmaxf((float)hD[0], 0.f), e1 = fmaxf((float)hD[1], 0.f);
            s0 += (a0 + b0) + (c0 + e0); s1 += (a1 + b1) + (c1 + e1);
            q0 = fmaf(a0, a0, q0); q0 = fmaf(b0, b0, q0);
            q0 = fmaf(c0, c0, q0); q0 = fmaf(e0, e0, q0);
            q1 = fmaf(a1, a1, q1); q1 = fmaf(b1, b1, q1);
            q1 = fmaf(c1, c1, q1); q1 = fmaf(e1, e1, q1);
        }
        for (; i < d; ++i){
            int sA = eps[r0 + i];
            f16x2 qA = *(const f16x2*)(PQ1 + (size_t)sA*256 + 128 + 2*lane);
            f16x2 hA = pv + qA;
            float a0 = fmaxf((float)hA[0], 0.f), a1 = fmaxf((float)hA[1], 0.f);
            s0 += a0; s1 += a1;
            q0 = fmaf(a0, a0, q0);
            q1 = fmaf(a1, a1, q1);
        }
    }
    __shared__ float bS0[256], bS1[256], bQ0[256], bQ1[256];
    bS0[tid] = s0; bS1[tid] = s1; bQ0[tid] = q0; bQ1[tid] = q1;
    __syncthreads();
    if (wave == 0){
        float a0 = bS0[lane] + bS0[64+lane] + bS0[128+lane] + bS0[192+lane];
        float a1 = bS1[lane] + bS1[64+lane] + bS1[128+lane] + bS1[192+lane];
        float c0 = bQ0[lane] + bQ0[64+lane] + bQ0[128+lane] + bQ0[192+lane];
        float c1 = bQ1[lane] + bQ1[64+lane] + bQ1[128+lane] + bQ1[192+lane];
        atomicAdd(&pblk[2*lane],       a0);
        atomicAdd(&pblk[2*lane + 1],   a1);
        atomicAdd(&pblk[128 + 2*lane],     c0);
        atomicAdd(&pblk[128 + 2*lane + 1], c1);
    }
}

__global__ void k_fold1(const float* __restrict__ g1a, const float* __restrict__ bt1a,
                        const float* __restrict__ W1b, const float* __restrict__ b1b,
                        float* __restrict__ pblk, float fE)
{
    __shared__ float tS[128];
    int tid = threadIdx.x;
    if (tid < 128){
        float m = pblk[tid] * fE;
        float q = pblk[128 + tid] * fE;
        float v = fmaxf(q - m*m, 0.f);
        float s = g1a[tid] * rsqrtf(v + EPSBN);
        float t = bt1a[tid] - m*s;
        pblk[512 + tid] = s;
        pblk[640 + tid] = t;
        tS[tid] = t;
    }
    __syncthreads();
    if (tid < 64){
        float acc = b1b[tid];
        for (int k = 0; k < 128; k++) acc = fmaf(tS[k], W1b[k*64 + tid], acc);
        pblk[768 + tid] = acc;
    }
}

// pass2p: pull GEMM-b, 2 edges/iter x 4 accumulators; readlane + fdot2.
// (R16/R18-proven: ~281us @ ~70% VALUBusy — the lane=channel issue floor.)
__global__ __launch_bounds__(256) void k_pass2p(
    const u16* __restrict__ PQ1, const int* __restrict__ eps,
    const int* __restrict__ cursor, const int* __restrict__ deg,
    const float* __restrict__ W1b,
    float* __restrict__ pblk, float* __restrict__ agg, int N)
{
    int tid = threadIdx.x;
    int lane = tid & 63, wave = tid >> 6;
    f16x2 wh[64];
    #pragma unroll
    for (int kk = 0; kk < 64; kk++){
        float w0 = pblk[512 + 2*kk]     * W1b[(2*kk)*64 + lane];
        float w1 = pblk[512 + 2*kk + 1] * W1b[(2*kk + 1)*64 + lane];
        f16x2 t; t[0] = (f16)w0; t[1] = (f16)w1;
        wh[kk] = t;
    }
    float bc = pblk[768 + lane];
    float runS = 0.f, runQ = 0.f;
    const f16 z0 = (f16)0;

    for (int n = blockIdx.x*4 + wave; n < N; n += gridDim.x*4){
        int d  = deg[n];
        int r0 = cursor[n] - d;
        f16x2 pv = *(const f16x2*)(PQ1 + (size_t)n*256 + 2*lane);
        float mh = -INFINITY;
        int i = 0;
        for (; i + 1 < d; i += 2){
            int sA = eps[r0 + i];
            int sB = eps[r0 + i + 1];
            f16x2 qA = *(const f16x2*)(PQ1 + (size_t)sA*256 + 128 + 2*lane);
            f16x2 qB = *(const f16x2*)(PQ1 + (size_t)sB*256 + 128 + 2*lane);
            f16x2 hA = pv + qA, hB = pv + qB;
            hA[0] = hA[0] > z0 ? hA[0] : z0;  hA[1] = hA[1] > z0 ? hA[1] : z0;
            hB[0] = hB[0] > z0 ? hB[0] : z0;  hB[1] = hB[1] > z0 ? hB[1] : z0;
            u32 hpA = __builtin_bit_cast(u32, hA);
            u32 hpB = __builtin_bit_cast(u32, hB);
            float aA[4] = {0.f,0.f,0.f,0.f};
            float aB[4] = {0.f,0.f,0.f,0.f};
            #pragma unroll
            for (int kk = 0; kk < 64; kk++){
                u32 xA = RLANE(hpA, kk);
                u32 xB = RLANE(hpB, kk);
                aA[kk & 3] = fdot2f(xA, wh[kk], aA[kk & 3]);
                aB[kk & 3] = fdot2f(xB, wh[kk], aB[kk & 3]);
            }
            float hbA = fmaxf((aA[0]+aA[1]) + (aA[2]+aA[3]) + bc, 0.f);
            float hbB = fmaxf((aB[0]+aB[1]) + (aB[2]+aB[3]) + bc, 0.f);
            runS += hbA + hbB;
            runQ = fmaf(hbA, hbA, runQ);
            runQ = fmaf(hbB, hbB, runQ);
            mh = fmaxf(mh, fmaxf(hbA, hbB));
        }
        if (i < d){
            int sA = eps[r0 + i];
            f16x2 qA = *(const f16x2*)(PQ1 + (size_t)sA*256 + 128 + 2*lane);
            f16x2 hA = pv + qA;
            hA[0] = hA[0] > z0 ? hA[0] : z0;  hA[1] = hA[1] > z0 ? hA[1] : z0;
            u32 hpA = __builtin_bit_cast(u32, hA);
            float aA[4] = {0.f,0.f,0.f,0.f};
            #pragma unroll
            for (int kk = 0; kk < 64; kk++){
                u32 xA = RLANE(hpA, kk);
                aA[kk & 3] = fdot2f(xA, wh[kk], aA[kk & 3]);
            }
            float hbA = fmaxf((aA[0]+aA[1]) + (aA[2]+aA[3]) + bc, 0.f);
            runS += hbA;
            runQ = fmaf(hbA, hbA, runQ);
            mh = fmaxf(mh, hbA);
        }
        if (d > 0) agg[(size_t)n*64 + lane] = mh;
    }
    __shared__ float bS[256], bQ[256];
    bS[tid] = runS; bQ[tid] = runQ;
    __syncthreads();
    if (wave == 0){
        float s = bS[lane] + bS[64+lane] + bS[128+lane] + bS[192+lane];
        float q = bQ[lane] + bQ[64+lane] + bQ[128+lane] + bQ[192+lane];
        atomicAdd(&pblk[256 + lane], s);
        atomicAdd(&pblk[320 + lane], q);
    }
}

// x1 = relu(bn1b(agg) or 0) -> x1b; BN1b affine computed inline from raw
// stats (fold_st absorbed). Resets agg to -inf for pass3p reuse.
__global__ void k_x1(float* __restrict__ agg, const float* __restrict__ pblk,
                     const float* __restrict__ g1b, const float* __restrict__ bt1b,
                     float fE, u16* __restrict__ x1b, int NF)
{
    int i = blockIdx.x*256 + threadIdx.x;
    if (i >= NF) return;
    int c = i & 63;
    float m = pblk[256 + c] * fE;
    float q = pblk[320 + c] * fE;
    float vv = fmaxf(q - m*m, 0.f);
    float s = g1b[c] * rsqrtf(vv + EPSBN);
    float t = bt1b[c] - m*s;
    float a = agg[i];
    float v = (a > -INFINITY) ? fmaf(a, s, t) : 0.f;
    v = fmaxf(v, 0.f);
    x1b[i] = (u16)f2bf1(v);
    agg[i] = -INFINITY;
}

// pass3p: pull conv2 (stats2 + segmax Q2), 4 edges/iter.
__global__ __launch_bounds__(256) void k_pass3p(
    const u16* __restrict__ PQ2, const int* __restrict__ eps,
    const int* __restrict__ cursor, const int* __restrict__ deg,
    float* __restrict__ pblk, float* __restrict__ agg, int N)
{
    int tid = threadIdx.x;
    int lane = tid & 63, wave = tid >> 6;
    float runS = 0.f, runQ = 0.f;

    for (int n = blockIdx.x*4 + wave; n < N; n += gridDim.x*4){
        int d  = deg[n];
        int r0 = cursor[n] - d;
        float p = bf2f(PQ2[(size_t)n*128 + lane]);
        float mq = -INFINITY;
        int i = 0;
        for (; i + 3 < d; i += 4){
            int sA = eps[r0+i], sB = eps[r0+i+1], sC = eps[r0+i+2], sD = eps[r0+i+3];
            float qA = bf2f(PQ2[(size_t)sA*128 + 64 + lane]);
            float qB = bf2f(PQ2[(size_t)sB*128 + 64 + lane]);
            float qC = bf2f(PQ2[(size_t)sC*128 + 64 + lane]);
            float qD = bf2f(PQ2[(size_t)sD*128 + 64 + lane]);
            mq = fmaxf(mq, fmaxf(fmaxf(qA, qB), fmaxf(qC, qD)));
            float hA = fmaxf(p + qA, 0.f), hB = fmaxf(p + qB, 0.f);
            float hC = fmaxf(p + qC, 0.f), hD = fmaxf(p + qD, 0.f);
            runS += (hA + hB) + (hC + hD);
            runQ = fmaf(hA, hA, runQ); runQ = fmaf(hB, hB, runQ);
            runQ = fmaf(hC, hC, runQ); runQ = fmaf(hD, hD, runQ);
        }
        for (; i < d; ++i){
            int sA = eps[r0 + i];
            float qA = bf2f(PQ2[(size_t)sA*128 + 64 + lane]);
            mq = fmaxf(mq, qA);
            float hA = fmaxf(p + qA, 0.f);
            runS += hA;
            runQ = fmaf(hA, hA, runQ);
        }
        if (d > 0) agg[(size_t)n*64 + lane] = mq;
    }
    __shared__ float bS[256], bQ[256];
    bS[tid] = runS; bQ[tid] = runQ;
    __syncthreads();
    if (wave == 0){
        float s = bS[lane] + bS[64 + lane] + bS[128 + lane] + bS[192 + lane];
        float q = bQ[lane] + bQ[64 + lane] + bQ[128 + lane] + bQ[192 + lane];
        atomicAdd(&pblk[384 + lane], s);
        atomicAdd(&pblk[448 + lane], q);
    }
}

// k_fuse: BN2 affine computed inline from raw stats (fold_st absorbed);
// x2 reconstructed from maxQ2+P2; per-run graph pooling.
#define FUSE_NODES 32
__global__ __launch_bounds__(256) void k_fuse(const float* __restrict__ agg,
                                              const u16* __restrict__ x1b,
                                              const u16* __restrict__ PQ2,
                                              const int* __restrict__ batch,
                                              const float* __restrict__ g2,
                                              const float* __restrict__ bt2,
                                              float fE,
                                              float* __restrict__ pblk, int N)
{
    int c = threadIdx.x & 63, r = threadIdx.x >> 6;
    int n0 = blockIdx.x*FUSE_NODES + r*(FUSE_NODES/4);
    if (n0 >= N) return;
    int n1 = n0 + FUSE_NODES/4; if (n1 > N) n1 = N;
    float m2 = pblk[384 + c] * fE;
    float q2 = pblk[448 + c] * fE;
    float vv = fmaxf(q2 - m2*m2, 0.f);
    float s2c = g2[c] * rsqrtf(vv + EPSBN);
    float t2c = bt2[c] - m2*s2c;
    float gm = -INFINITY, gs = 0.f;
    int cur = batch[n0], cnt0 = 0;
    for (int n = n0; n < n1; ++n){
        int g = batch[n];
        if (g != cur){
            atomicMaxF(&pblk[1088 + cur*64 + c], gm);
            atomicAdd(&pblk[5184 + cur*64 + c], gs);
            if (c == 0) atomicAdd(&pblk[9280 + cur], (float)cnt0);
            gm = -INFINITY; gs = 0.f; cnt0 = 0; cur = g;
        }
        float a = agg[(size_t)n*64 + c];   // maxQ2 (or -inf if no in-edges)
        float v;
        if (a > -INFINITY){
            float p = bf2f(PQ2[(size_t)n*128 + c]);
            float pre = fmaxf(p + a, 0.f);
            v = fmaxf(fmaf(pre, s2c, t2c), 0.f);
        } else v = 0.f;
        float f = bf2f(x1b[(size_t)n*64 + c]) + v;
        gm = fmaxf(gm, f); gs += f; cnt0++;
    }
    atomicMaxF(&pblk[1088 + cur*64 + c], gm);
    atomicAdd(&pblk[5184 + cur*64 + c], gs);
    if (c == 0) atomicAdd(&pblk[9280 + cur], (float)cnt0);
}

__global__ void k_out(const float* __restrict__ pblk, float* __restrict__ out)
{
    int i = blockIdx.x*256 + threadIdx.x;
    if (i >= 64*128) return;
    int g = i >> 7, c = i & 127;
    float r;
    if (c < 64){
        float m = pblk[1088 + g*64 + c];
        r = (m > -INFINITY) ? m : 0.f;
    } else {
        float s = pblk[5184 + g*64 + (c - 64)];
        float n = pblk[9280 + g];
        r = s / fmaxf(n, 1.f);
    }
    out[i] = r;
}

extern "C" void kernel_launch(void* const* d_in, const int* in_sizes, int n_in,
                              void* d_out, int out_size, void* d_ws, size_t ws_size,
                              hipStream_t stream)
{
    const float* x    = (const float*)d_in[0];
    const int*   ei   = (const int*)  d_in[1];
    const int*   batch= (const int*)  d_in[2];
    const float* W1a  = (const float*)d_in[3];
    const float* b1a  = (const float*)d_in[4];
    const float* g1a  = (const float*)d_in[5];
    const float* bt1a = (const float*)d_in[6];
    const float* W1b  = (const float*)d_in[7];
    const float* b1b  = (const float*)d_in[8];
    const float* g1b  = (const float*)d_in[9];
    const float* bt1b = (const float*)d_in[10];
    const float* W2   = (const float*)d_in[11];
    const float* b2   = (const float*)d_in[12];
    const float* g2   = (const float*)d_in[13];
    const float* bt2  = (const float*)d_in[14];

    int N  = in_sizes[0] / 64;
    int E  = in_sizes[1] / 2;
    int NF = N * 64;

    char* ws = (char*)d_ws;
    size_t off = 0;
    auto alloc = [&](size_t bytes){ size_t o = off; off += (bytes + 255) & ~(size_t)255; return o; };
    u16*   xb    = (u16*)  (ws + alloc((size_t)NF*2));
    u16*   x1b   = (u16*)  (ws + alloc((size_t)NF*2));
    float* agg   = (float*)(ws + alloc((size_t)NF*4));
    float* pblk  = (float*)(ws + alloc((size_t)PB_TOT*4));
    int*   deg   = (int*)  (ws + alloc((size_t)N*4));
    int*   cursor= (int*)  (ws + alloc((size_t)N*4));
    int*   eps   = (int*)  (ws + alloc((size_t)E*4));
    u16*   PQ1   = (u16*)  (ws + alloc((size_t)N*256*2));
    u16*   PQ2   = (u16*)  (ws + alloc((size_t)N*128*2));
    int*   bsum  = (int*)  (ws + alloc((size_t)1024*4));
    int*   boff  = (int*)  (ws + alloc((size_t)1024*4));
    (void)ws_size;   // ~68MB << proven 237.7MB budget

    const int* esrc = ei;
    const int* edst = ei + E;
    int gElem  = (NF + 255) / 256;
    int gEdge  = (E + 255) / 256;
    int gNode  = (N + 63) / 64;
    int gScan  = (N + 1023) / 1024;
    int gPull  = ((N + 3) / 4) < 2048 ? ((N + 3) / 4) : 2048;
    float fE   = 1.f / (float)E;

    k_init        <<<gElem, 256, 0, stream>>>(x, xb, agg, pblk, deg, NF, N);
    k_hist        <<<gEdge, 256, 0, stream>>>(edst, deg, E);
    k_scanA       <<<gScan, 1024, 0, stream>>>(deg, cursor, bsum, N);
    k_scanB       <<<1, 64, 0, stream>>>(bsum, boff, gScan);
    k_scanC       <<<gScan, 1024, 0, stream>>>(cursor, boff, N);
    k_scatter     <<<gEdge, 256, 0, stream>>>(esrc, edst, cursor, eps, E);
    k_ngemm<256,1><<<gNode, 256, 0, stream>>>(xb, W1a, b1a, PQ1, N);
    k_pass1p      <<<gPull, 256, 0, stream>>>(PQ1, eps, cursor, deg, pblk, N);
    k_fold1       <<<1, 128, 0, stream>>>(g1a, bt1a, W1b, b1b, pblk, fE);
    k_pass2p      <<<gPull, 256, 0, stream>>>(PQ1, eps, cursor, deg, W1b, pblk, agg, N);
    k_x1          <<<gElem, 256, 0, stream>>>(agg, pblk, g1b, bt1b, fE, x1b, NF);
    k_ngemm<128,0><<<gNode, 256, 0, stream>>>(x1b, W2, b2, PQ2, N);
    k_pass3p      <<<gPull, 256, 0, stream>>>(PQ2, eps, cursor, deg, pblk, agg, N);
    k_fuse        <<<(N + FUSE_NODES - 1)/FUSE_NODES, 256, 0, stream>>>(agg, x1b, PQ2, batch, g2, bt2, fE, pblk, N);
    k_out         <<<32, 256, 0, stream>>>(pblk, (float*)d_out);
}